// Round 8
// baseline (32.556 us; speedup 1.0000x reference)
//
#include <hip/hip_runtime.h>

#define MARGIN 0.1f
#define EPSF   1e-12f
#define BB 32
#define NN 2048
#define DD 128

// ws layout: dist[BB*NN] f32 | partials[BB*8] f32 | row_loss[BB] f32 |
//            tick_b[BB] int | tick_g[1] int
// Determinism: every float sum is fixed-order; every global cell single-writer.

// Kernel 1: dist[b][n]. 32-lane group per row, float4 loads. Resets tickets.
__global__ __launch_bounds__(256) void dist_kernel(const float* __restrict__ anchors,
                                                   const float* __restrict__ feats,
                                                   float* __restrict__ dist,
                                                   int* __restrict__ tick_b,
                                                   int* __restrict__ tick_g) {
    const int chunk = blockIdx.x;   // 0..31 (64 rows each)
    const int b     = blockIdx.y;   // 0..31
    const int t     = threadIdx.x;
    const int g     = t >> 5;       // group 0..7
    const int sub   = t & 31;       // lane within group

    if (chunk == 0 && b == 0) {
        if (t < BB) tick_b[t] = 0;
        if (t == BB) *tick_g = 0;
    }

    const float4 a4 = ((const float4*)(anchors + b * DD))[sub];
    float a2 = a4.x*a4.x + a4.y*a4.y + a4.z*a4.z + a4.w*a4.w;
    #pragma unroll
    for (int m = 16; m >= 1; m >>= 1) a2 += __shfl_xor(a2, m);
    const float ra    = sqrtf(a2);
    const float inva  = 1.0f / (ra + EPSF);
    const float s_anc = (ra * inva) * (ra * inva);

    const float* fp = feats + ((size_t)b * NN) * DD;
    #pragma unroll
    for (int it = 0; it < 8; ++it) {
        const int n = chunk * 64 + it * 8 + g;
        const float4 f4 = ((const float4*)(fp + (size_t)n * DD))[sub];
        float ss = f4.x*f4.x + f4.y*f4.y + f4.z*f4.z + f4.w*f4.w;
        float dt = a4.x*f4.x + a4.y*f4.y + a4.z*f4.z + a4.w*f4.w;
        #pragma unroll
        for (int m = 16; m >= 1; m >>= 1) {
            ss += __shfl_xor(ss, m);
            dt += __shfl_xor(dt, m);
        }
        const float rf   = sqrtf(ss);
        const float invf = 1.0f / (rf + EPSF);
        const float sq   = s_anc + (rf*invf)*(rf*invf) - 2.0f * dt * inva * invf;
        const float dd   = sqrtf(fmaxf(sq, 1e-12f));
        if (sub == 0) dist[b * NN + n] = dd;
    }
}

// Kernel 2: deterministic compacted pair loss, 256 blocks (8 chunks x 32 b) x 256.
// Hierarchical fan-in: per-b ticket (8 parts, distinct cells) -> global ticket (32).
__global__ __launch_bounds__(256) void pair_kernel(const float* __restrict__ dist,
                                                   const int* __restrict__ tgt,
                                                   float* __restrict__ partials,
                                                   float* __restrict__ row_loss,
                                                   int* __restrict__ tick_b,
                                                   int* __restrict__ tick_g,
                                                   float* __restrict__ out) {
    __shared__ float sd[NN + 32];
    __shared__ float pd[256];
    __shared__ int   cntk[32], posk[32], pref[33];
    __shared__ int   pcnt[4], ppref[5];
    __shared__ int   np_sh, lastflag;
    __shared__ float sred[4];

    const int chunk = blockIdx.x;   // 0..7 (256 i-rows each)
    const int b     = blockIdx.y;   // 0..31
    const int t     = threadIdx.x;
    const int lane  = t & 63;
    const int w     = t >> 6;       // wave 0..3

    const float* db = dist + b * NN;
    const int*   tb = tgt  + b * NN;

    // Pass 1: full-row flags + per-(k,wave) counts (fixed j-order q = k*4+w).
    float dvv[8]; bool ngg[8];
    #pragma unroll
    for (int k = 0; k < 8; ++k) {
        const int j  = k * 256 + t;
        dvv[k] = db[j];
        const int tv = tb[j];
        ngg[k] = (tv == 0);
        const bool pos = (tv > 0);
        const unsigned long long nm = __ballot(ngg[k]);
        const unsigned long long pm = __ballot(pos);
        if (lane == 0) { cntk[k * 4 + w] = __popcll(nm); posk[k * 4 + w] = __popcll(pm); }
        if (k == chunk && lane == 0) pcnt[w] = __popcll(pm);   // own-chunk positives
    }
    __syncthreads();
    if (t == 0) {   // serial exclusive prefixes in fixed order: deterministic
        int run = 0, pp = 0;
        #pragma unroll
        for (int q = 0; q < 32; ++q) { pref[q] = run; run += cntk[q]; pp += posk[q]; }
        pref[32] = run;
        np_sh    = pp;
        int pr = 0;
        #pragma unroll
        for (int q = 0; q < 4; ++q) { ppref[q] = pr; pr += pcnt[q]; }
        ppref[4] = pr;
    }
    __syncthreads();

    // Pass 2: scatter at deterministic offsets (sd sorted by j, pd by i).
    #pragma unroll
    for (int k = 0; k < 8; ++k) {
        const unsigned long long nm = __ballot(ngg[k]);
        if (ngg[k]) sd[pref[k * 4 + w] + __popcll(nm & ((1ull << lane) - 1))] = dvv[k];
        if (k == chunk) {
            const bool posi = !ngg[k] && (tb[k * 256 + t] > 0);
            const unsigned long long pm = __ballot(posi);
            if (posi) pd[ppref[w] + __popcll(pm & ((1ull << lane) - 1))] = dvv[k];
        }
    }
    __syncthreads();

    const int nn     = pref[32];
    const int np     = np_sh;
    const int npb    = ppref[4];
    const int nn_pad = (nn + 31) & ~31;   // multiple of 32 floats = 8 float4s
    for (int x = t; x < nn_pad - nn; x += 256) sd[nn + x] = 1e30f;   // sentinels
    __syncthreads();

    // Octet layout: 8 threads per positive slot, interleaved float4 j-stripes.
    float acc = 0.0f;
    {
        const int     s   = t & 7;
        const float4* s4  = (const float4*)sd;
        const int     nf4 = nn_pad >> 2;
        for (int p = t >> 3; p < npb; p += 32) {
            const float x = pd[p] + MARGIN;
            float a0 = 0.f, a1 = 0.f, a2_ = 0.f, a3 = 0.f;
            #pragma unroll 4
            for (int f = s; f < nf4; f += 8) {
                const float4 q = s4[f];    // 8 distinct 16B lines -> all 32 banks, broadcast
                a0  += fmaxf(x - q.x, 0.0f);
                a1  += fmaxf(x - q.y, 0.0f);
                a2_ += fmaxf(x - q.z, 0.0f);
                a3  += fmaxf(x - q.w, 0.0f);
            }
            acc += (a0 + a1) + (a2_ + a3);
        }
    }

    #pragma unroll
    for (int m = 32; m >= 1; m >>= 1) acc += __shfl_xor(acc, m);
    if (lane == 0) sred[w] = acc;
    __syncthreads();

    // Hierarchical fan-in (all single-writer cells, fixed-order sums).
    if (t == 0) {
        const float bsum = (sred[0] + sred[1]) + (sred[2] + sred[3]);
        atomicExch(&partials[b * 8 + chunk], bsum);
        __threadfence();
        int lf = 0;
        if (atomicAdd(&tick_b[b], 1) == 7) {          // last of this b
            __threadfence();
            float rs = 0.0f;
            #pragma unroll
            for (int c = 0; c < 8; ++c) rs += atomicAdd(&partials[b * 8 + c], 0.0f);
            const float den = fmaxf((float)np * (float)nn, 1.0f);
            const float v = (np > 0) ? rs / den : MARGIN;
            atomicExch(&row_loss[b], v);
            __threadfence();
            lf = (atomicAdd(tick_g, 1) == BB - 1);    // last of all
        }
        lastflag = lf;
    }
    __syncthreads();

    if (lastflag) {
        __threadfence();
        float v = 0.0f;
        if (t < BB) v = atomicAdd(&row_loss[t], 0.0f);
        if (t < 64) {
            #pragma unroll
            for (int m = 32; m >= 1; m >>= 1) v += __shfl_xor(v, m);
            if (t == 0) out[0] = v;
        }
    }
}

extern "C" void kernel_launch(void* const* d_in, const int* in_sizes, int n_in,
                              void* d_out, int out_size, void* d_ws, size_t ws_size,
                              hipStream_t stream) {
    const float* anchors = (const float*)d_in[0];
    const float* feats   = (const float*)d_in[1];
    const int*   tgt     = (const int*)d_in[2];
    float*       out     = (float*)d_out;

    float* dist     = (float*)d_ws;                 // BB*NN floats
    float* partials = dist + BB * NN;               // BB*8 floats
    float* row_loss = partials + BB * 8;            // BB floats
    int*   tick_b   = (int*)(row_loss + BB);        // BB ints
    int*   tick_g   = tick_b + BB;                  // 1 int

    dist_kernel<<<dim3(32, 32), 256, 0, stream>>>(anchors, feats, dist, tick_b, tick_g);
    pair_kernel<<<dim3(8, 32), 256, 0, stream>>>(dist, tgt, partials, row_loss,
                                                 tick_b, tick_g, out);
}